// Round 9
// baseline (138.577 us; speedup 1.0000x reference)
//
#include <hip/hip_runtime.h>
#include <math.h>

#define Bn 256
#define Sn 512
#define En 768
#define G3n 2304
#define TAIL_BLOCKS 192
#define GRP 24          // blocks per m-group (e-tiles)

typedef __attribute__((ext_vector_type(8))) short short8;   // 8 bf16 in 4 VGPRs
typedef __attribute__((ext_vector_type(4))) float f32x4;

__device__ __forceinline__ float sigmoidf_(float x) { return 1.f / (1.f + __expf(-x)); }
__device__ __forceinline__ float tanhf_(float x) {
  float e = __expf(2.f * x);
  return (e - 1.f) / (e + 1.f);
}

__device__ __forceinline__ unsigned short f2bf(float x) {
  unsigned int u = __builtin_bit_cast(unsigned int, x);
  u += 0x7FFFu + ((u >> 16) & 1u);          // round-to-nearest-even
  return (unsigned short)(u >> 16);
}
__device__ __forceinline__ float bf2f(unsigned short u) {
  unsigned int x = ((unsigned int)u) << 16;
  return __builtin_bit_cast(float, x);
}

// location weighting: u (position feature), w (memory weight)
__device__ __forceinline__ void loc_uw(int s, int start, int al, int ml, float& u, float& w) {
  float uu;
  if (s < start)            uu = (float)(s - start);
  else if (s < start + al)  uu = 0.f;
  else                      uu = (float)(s - start - al + 1);
  float l = fabsf(uu);
  if (s < ml) { w = 1.f - l / (float)ml; u = uu; }
  else        { w = 1.f; u = 0.f; }
}

// group barrier: device-scope atomic arrive + spin; release/acquire fences for
// cross-XCD visibility of the normal stores made before arrival.
__device__ __forceinline__ void group_barrier(unsigned int* cnt, unsigned int expected) {
  __syncthreads();
  if (threadIdx.x == 0) {
    __threadfence();    // release: flush this block's stores device-wide
    __hip_atomic_fetch_add(cnt, 1u, __ATOMIC_ACQ_REL, __HIP_MEMORY_SCOPE_AGENT);
    while (__hip_atomic_load(cnt, __ATOMIC_ACQUIRE, __HIP_MEMORY_SCOPE_AGENT) < expected)
      __builtin_amdgcn_s_sleep(2);
    __threadfence();    // acquire: invalidate stale lines before group reads
  }
  __syncthreads();
}

// ================ K1: mega kernel =================
// blocks [0,512):  attention halves — block = (b, half of 256 rows), 16 waves,
//                  16 rows/wave online softmax; emits unnormalized (M,Z,IU,acc).
// blocks [512,944): GRU weight conversion f32 -> bf16 (216 blocks per matrix).
// block 512 additionally seeds out[] = dense_b and zeroes the barrier counters.
__global__ __launch_bounds__(1024) void k_mega(
    const float* __restrict__ mem, const float* __restrict__ att_w,
    const int* __restrict__ mlen, const int* __restrict__ llen, const int* __restrict__ alen,
    const float* __restrict__ w_ih, const float* __restrict__ w_hh,
    float* __restrict__ pacc, float* __restrict__ pm,
    float* __restrict__ pz, float* __restrict__ piu,
    unsigned short* __restrict__ wi_bf, unsigned short* __restrict__ wh_bf,
    const float* __restrict__ db, float* __restrict__ out,
    unsigned int* __restrict__ barcnt) {
  __shared__ float accL[16][En];
  __shared__ float mL[16], zL[16], iuL[16];
  int bc = blockIdx.x;
  int tid = threadIdx.x;

  if (bc >= 512) {
    // ---- weight conversion role ----
    int cb = bc - 512;                 // [0,432)
    int mat = cb >= 216;
    int t = (cb - mat * 216) * 1024 + tid;
    int idx = t * 8;                   // [0, 2304*768)
    int r = idx / En, c = idx - r * En;
    const float* src;
    unsigned short* dst;
    if (mat == 0) { src = w_ih + (size_t)r * 769 + c; dst = wi_bf + idx; }
    else          { src = w_hh + (size_t)r * En  + c; dst = wh_bf + idx; }
    unsigned int p[4];
#pragma unroll
    for (int j = 0; j < 4; ++j) {
      unsigned int lo = f2bf(src[2 * j]);
      unsigned int hi = f2bf(src[2 * j + 1]);
      p[j] = lo | (hi << 16);
    }
    *reinterpret_cast<uint4*>(dst) = make_uint4(p[0], p[1], p[2], p[3]);
    if (bc == 512) {
      if (tid < 768)                 out[tid] = db[tid % 3];      // seed logits bias
      else if (tid < 768 + 16)       barcnt[tid - 768] = 0u;      // reset barriers
    }
    return;
  }

  // ---- attention role ----
  int b = bc >> 1, half = bc & 1;
  int wv = tid >> 6, lane = tid & 63;

  float4 w0 = *reinterpret_cast<const float4*>(att_w + lane * 4);
  float4 w1 = *reinterpret_cast<const float4*>(att_w + 256 + lane * 4);
  float4 w2 = *reinterpret_cast<const float4*>(att_w + 512 + lane * 4);
  float wtail = att_w[En];
  int start = llen[b], al = alen[b], ml = mlen[b];
  int s0row = half * 256 + wv * 16;
  const float* base = mem + ((size_t)b * Sn + s0row) * En;

  float m = -1e30f, z = 0.f, iu = 0.f;
  float4 a0 = {0, 0, 0, 0}, a1 = {0, 0, 0, 0}, a2 = {0, 0, 0, 0};
  float4 v0 = *reinterpret_cast<const float4*>(base + lane * 4);
  float4 v1 = *reinterpret_cast<const float4*>(base + 256 + lane * 4);
  float4 v2 = *reinterpret_cast<const float4*>(base + 512 + lane * 4);

  for (int r = 0; r < 16; ++r) {
    float4 c0 = v0, c1 = v1, c2 = v2;
    if (r < 15) {
      const float* nrow = base + (size_t)(r + 1) * En;
      v0 = *reinterpret_cast<const float4*>(nrow + lane * 4);
      v1 = *reinterpret_cast<const float4*>(nrow + 256 + lane * 4);
      v2 = *reinterpret_cast<const float4*>(nrow + 512 + lane * 4);
    }
    float dot = c0.x * w0.x + c0.y * w0.y + c0.z * w0.z + c0.w * w0.w
              + c1.x * w1.x + c1.y * w1.y + c1.z * w1.z + c1.w * w1.w
              + c2.x * w2.x + c2.y * w2.y + c2.z * w2.z + c2.w * w2.w;
#pragma unroll
    for (int off = 32; off; off >>= 1) dot += __shfl_xor(dot, off);
    int s = s0row + r;
    float u, w;
    loc_uw(s, start, al, ml, u, w);
    float g = w * dot + u * wtail;
    if (g > m) {                       // wave-uniform branch
      float f = __expf(m - g);         // first row: exp(-inf) = 0
      z *= f; iu *= f;
      a0.x *= f; a0.y *= f; a0.z *= f; a0.w *= f;
      a1.x *= f; a1.y *= f; a1.z *= f; a1.w *= f;
      a2.x *= f; a2.y *= f; a2.z *= f; a2.w *= f;
      m = g;
    }
    float e = __expf(g - m);
    z += e; iu += e * u;
    float sc = e * w;
    a0.x += sc * c0.x; a0.y += sc * c0.y; a0.z += sc * c0.z; a0.w += sc * c0.w;
    a1.x += sc * c1.x; a1.y += sc * c1.y; a1.z += sc * c1.z; a1.w += sc * c1.w;
    a2.x += sc * c2.x; a2.y += sc * c2.y; a2.z += sc * c2.z; a2.w += sc * c2.w;
  }

  *reinterpret_cast<float4*>(&accL[wv][lane * 4])       = a0;
  *reinterpret_cast<float4*>(&accL[wv][256 + lane * 4]) = a1;
  *reinterpret_cast<float4*>(&accL[wv][512 + lane * 4]) = a2;
  if (lane == 0) { mL[wv] = m; zL[wv] = z; iuL[wv] = iu; }
  __syncthreads();

  float M = mL[0];
#pragma unroll
  for (int i = 1; i < 16; ++i) M = fmaxf(M, mL[i]);
  float f[16], Z = 0.f, IU = 0.f;
#pragma unroll
  for (int i = 0; i < 16; ++i) {
    f[i] = __expf(mL[i] - M);
    Z += zL[i] * f[i];
    IU += iuL[i] * f[i];
  }
  if (tid < En) {
    float s = 0.f;
#pragma unroll
    for (int i = 0; i < 16; ++i) s += f[i] * accL[i][tid];
    pacc[(size_t)bc * En + tid] = s;
  }
  if (tid == 0) { pm[bc] = M; pz[bc] = Z; piu[bc] = IU; }
}

// ================ K2: persistent tail kernel =================
// 192 blocks x 512 thr (8 waves, 2-way split-K as R8). Block = (mgrp, e-tile):
// m0 = (bid/24)*32, e0 = (bid%24)*32. Runs hop0 (A = inline softmax-combine of
// pacc), group-barrier(24), hop1 (A = eta), group-barrier, hop2 (A = etb) with
// fused logits. gi / et cross the barriers; everything a group reads is written
// by its own 24 blocks.
__global__ __launch_bounds__(512) void k_tail(
    const float* __restrict__ pacc, const float* __restrict__ pm,
    const float* __restrict__ pz, const float* __restrict__ piu,
    const unsigned short* __restrict__ wi_bf, const unsigned short* __restrict__ wh_bf,
    const float* __restrict__ w_ih, const float* __restrict__ b_ih,
    const float* __restrict__ b_hh, float* __restrict__ gi,
    unsigned short* __restrict__ eta_bf, unsigned short* __restrict__ etb_bf,
    const float* __restrict__ dw, float* __restrict__ out,
    unsigned int* __restrict__ barcnt) {
  __shared__ unsigned short As[32][264];
  __shared__ unsigned short Bs[3][32][264];
  __shared__ float red[4][64][17];
  __shared__ float rowF0[32], rowF1[32], rowAu[32];
  int bid = blockIdx.x;
  int mgrp = bid / GRP;
  int e0 = (bid - mgrp * GRP) * 32, m0 = mgrp * 32;
  int tid = threadIdx.x;
  int lane = tid & 63, wv = tid >> 6;
  int p = wv & 3, kh = wv >> 2;
  int wm = p >> 1, we = p & 1;
  int l15 = lane & 15, l4 = lane >> 4;

  // per-row softmax-combine constants (hop 0 only); inv folded into f0/f1
  if (tid < 32) {
    int m = m0 + tid;
    float ma = pm[2 * m], mb = pm[2 * m + 1];
    float M = fmaxf(ma, mb);
    float f0 = __expf(ma - M), f1 = __expf(mb - M);
    float iv = 1.f / (pz[2 * m] * f0 + pz[2 * m + 1] * f1);
    rowF0[tid] = f0 * iv;
    rowF1[tid] = f1 * iv;
    rowAu[tid] = (piu[2 * m] * f0 + piu[2 * m + 1] * f1) * iv;
  }

  for (int hop = 0; hop < 3; ++hop) {
    const unsigned short* Wbf = (hop == 0) ? wi_bf : wh_bf;
    const unsigned short* Abf = (hop == 1) ? eta_bf : etb_bf;   // hop0: unused

    f32x4 acc[3];
#pragma unroll
    for (int g = 0; g < 3; ++g) { acc[g][0] = 0.f; acc[g][1] = 0.f; acc[g][2] = 0.f; acc[g][3] = 0.f; }

    for (int kb = 0; kb < 3; ++kb) {
      int kbase = kb * 256;
      __syncthreads();
      if (hop == 0) {
#pragma unroll
        for (int i = 0; i < 2; ++i) {
          int idx = tid + i * 512;           // 32 rows x 32 chunks
          int row = idx >> 5, ch = idx & 31;
          float f0 = rowF0[row], f1 = rowF1[row];
          const float* q0 = pacc + (size_t)(2 * (m0 + row)) * En + kbase + ch * 8;
          const float* q1 = q0 + En;
          float4 x0 = *reinterpret_cast<const float4*>(q0);
          float4 x1 = *reinterpret_cast<const float4*>(q0 + 4);
          float4 y0 = *reinterpret_cast<const float4*>(q1);
          float4 y1 = *reinterpret_cast<const float4*>(q1 + 4);
          unsigned int pk[4];
          pk[0] = (unsigned int)f2bf(f0 * x0.x + f1 * y0.x)
                | ((unsigned int)f2bf(f0 * x0.y + f1 * y0.y) << 16);
          pk[1] = (unsigned int)f2bf(f0 * x0.z + f1 * y0.z)
                | ((unsigned int)f2bf(f0 * x0.w + f1 * y0.w) << 16);
          pk[2] = (unsigned int)f2bf(f0 * x1.x + f1 * y1.x)
                | ((unsigned int)f2bf(f0 * x1.y + f1 * y1.y) << 16);
          pk[3] = (unsigned int)f2bf(f0 * x1.z + f1 * y1.z)
                | ((unsigned int)f2bf(f0 * x1.w + f1 * y1.w) << 16);
          *reinterpret_cast<uint4*>(&As[row][ch * 8]) = make_uint4(pk[0], pk[1], pk[2], pk[3]);
        }
      } else {
#pragma unroll
        for (int i = 0; i < 2; ++i) {
          int idx = tid + i * 512;
          int row = idx >> 5, ch = idx & 31;
          *reinterpret_cast<uint4*>(&As[row][ch * 8]) =
              *reinterpret_cast<const uint4*>(Abf + (size_t)(m0 + row) * En + kbase + ch * 8);
        }
      }
#pragma unroll
      for (int i = 0; i < 6; ++i) {
        int idx = tid + i * 512;             // 3 gates x 32 rows x 32 chunks
        int g = idx >> 10, rem = idx & 1023;
        int row = rem >> 5, ch = rem & 31;
        *reinterpret_cast<uint4*>(&Bs[g][row][ch * 8]) =
            *reinterpret_cast<const uint4*>(Wbf + (size_t)(g * En + e0 + row) * En + kbase + ch * 8);
      }
      __syncthreads();
#pragma unroll
      for (int ks = 0; ks < 4; ++ks) {
        int col = kh * 128 + ks * 32 + l4 * 8;
        short8 a = *reinterpret_cast<const short8*>(&As[wm * 16 + l15][col]);
#pragma unroll
        for (int g = 0; g < 3; ++g) {
          short8 bfr = *reinterpret_cast<const short8*>(&Bs[g][we * 16 + l15][col]);
          acc[g] = __builtin_amdgcn_mfma_f32_16x16x32_bf16(a, bfr, acc[g], 0, 0, 0);
        }
      }
    }

    // ---- split-K reduce: kh=1 waves deposit, kh=0 waves merge + epilogue ----
    __syncthreads();    // protect red[] reuse across hops
    if (kh == 1) {
#pragma unroll
      for (int g = 0; g < 3; ++g)
#pragma unroll
        for (int j = 0; j < 4; ++j) red[p][lane][g * 4 + j] = acc[g][j];
    }
    __syncthreads();
    if (kh == 0) {
#pragma unroll
      for (int g = 0; g < 3; ++g)
#pragma unroll
        for (int j = 0; j < 4; ++j) acc[g][j] += red[p][lane][g * 4 + j];

      int ecol = e0 + we * 16 + l15;
      int mbase = m0 + wm * 16 + l4 * 4;
      float bhr = b_hh[ecol], bhz = b_hh[En + ecol], bhn = b_hh[2 * En + ecol];
      float vout[4];
      if (hop == 0) {
        float wn0 = w_ih[(size_t)ecol * 769 + En];
        float wn1 = w_ih[(size_t)(En + ecol) * 769 + En];
        float wn2 = w_ih[(size_t)(2 * En + ecol) * 769 + En];
        float bi0 = b_ih[ecol], bi1 = b_ih[En + ecol], bi2 = b_ih[2 * En + ecol];
#pragma unroll
        for (int j = 0; j < 4; ++j) {
          int m = mbase + j;
          float au = rowAu[wm * 16 + l4 * 4 + j];
          float gr = acc[0][j] + au * wn0 + bi0;
          float gz = acc[1][j] + au * wn1 + bi1;
          float gn = acc[2][j] + au * wn2 + bi2;
          gi[(size_t)m * G3n + ecol]          = gr;
          gi[(size_t)m * G3n + En + ecol]     = gz;
          gi[(size_t)m * G3n + 2 * En + ecol] = gn;
          float r = sigmoidf_(gr + bhr);
          float z = sigmoidf_(gz + bhz);
          float n = tanhf_(gn + r * bhn);
          vout[j] = (1.f - z) * n;
          eta_bf[(size_t)m * En + ecol] = f2bf(vout[j]);
        }
      } else {
#pragma unroll
        for (int j = 0; j < 4; ++j) {
          int m = mbase + j;
          float rr = sigmoidf_(gi[(size_t)m * G3n + ecol] + acc[0][j] + bhr);
          float zz = sigmoidf_(gi[(size_t)m * G3n + En + ecol] + acc[1][j] + bhz);
          float nn = tanhf_(gi[(size_t)m * G3n + 2 * En + ecol] + rr * (acc[2][j] + bhn));
          float h = bf2f(Abf[(size_t)m * En + ecol]);   // A IS et_in
          vout[j] = (1.f - zz) * nn + zz * h;
        }
        if (hop == 1) {
#pragma unroll
          for (int j = 0; j < 4; ++j)
            etb_bf[(size_t)(mbase + j) * En + ecol] = f2bf(vout[j]);
        } else {
          // fused logits: 16-lane row-group reduce, one atomicAdd per (row,out)
          float dw0 = dw[ecol * 3 + 0], dw1 = dw[ecol * 3 + 1], dw2 = dw[ecol * 3 + 2];
          float pp[4][3];
#pragma unroll
          for (int j = 0; j < 4; ++j) {
            pp[j][0] = vout[j] * dw0;
            pp[j][1] = vout[j] * dw1;
            pp[j][2] = vout[j] * dw2;
          }
#pragma unroll
          for (int off = 1; off < 16; off <<= 1)
#pragma unroll
            for (int j = 0; j < 4; ++j) {
              pp[j][0] += __shfl_xor(pp[j][0], off);
              pp[j][1] += __shfl_xor(pp[j][1], off);
              pp[j][2] += __shfl_xor(pp[j][2], off);
            }
          if (l15 == 0) {
#pragma unroll
            for (int j = 0; j < 4; ++j) {
              atomicAdd(&out[(mbase + j) * 3 + 0], pp[j][0]);
              atomicAdd(&out[(mbase + j) * 3 + 1], pp[j][1]);
              atomicAdd(&out[(mbase + j) * 3 + 2], pp[j][2]);
            }
          }
        }
      }
    }
    if (hop < 2) group_barrier(&barcnt[hop * 8 + mgrp], GRP);
  }
}

extern "C" void kernel_launch(void* const* d_in, const int* in_sizes, int n_in,
                              void* d_out, int out_size, void* d_ws, size_t ws_size,
                              hipStream_t stream) {
  const float* memory   = (const float*)d_in[0];
  const float* att_w    = (const float*)d_in[2];
  const float* gru_w_ih = (const float*)d_in[4];
  const float* gru_w_hh = (const float*)d_in[5];
  const float* gru_b_ih = (const float*)d_in[6];
  const float* gru_b_hh = (const float*)d_in[7];
  const float* dense_w  = (const float*)d_in[8];
  const float* dense_b  = (const float*)d_in[9];
  const int* memory_len = (const int*)d_in[10];
  const int* left_len   = (const int*)d_in[11];
  const int* aspect_len = (const int*)d_in[12];
  float* out = (float*)d_out;

  unsigned short* wi_bf  = (unsigned short*)d_ws;               // 2304*768
  unsigned short* wh_bf  = wi_bf + (size_t)G3n * En;            // 2304*768
  unsigned short* eta_bf = wh_bf + (size_t)G3n * En;            // 256*768
  unsigned short* etb_bf = eta_bf + (size_t)Bn * En;            // 256*768
  float* pm     = (float*)(etb_bf + (size_t)Bn * En);           // 512
  float* pz     = pm + 2 * Bn;                                  // 512
  float* piu    = pz + 2 * Bn;                                  // 512
  float* pacc   = piu + 2 * Bn;                                 // 512*768
  float* gi     = pacc + (size_t)2 * Bn * En;                   // 256*2304
  unsigned int* barcnt = (unsigned int*)(gi + (size_t)Bn * G3n);// 16

  k_mega<<<dim3(944), 1024, 0, stream>>>(memory, att_w, memory_len, left_len, aspect_len,
                                         gru_w_ih, gru_w_hh, pacc, pm, pz, piu, wi_bf, wh_bf,
                                         dense_b, out, barcnt);
  k_tail<<<dim3(TAIL_BLOCKS), 512, 0, stream>>>(pacc, pm, pz, piu, wi_bf, wh_bf,
                                                gru_w_ih, gru_b_ih, gru_b_hh, gi,
                                                eta_bf, etb_bf, dense_w, out, barcnt);
}

// Round 10
// 116.500 us; speedup vs baseline: 1.1895x; 1.1895x over previous
//
#include <hip/hip_runtime.h>
#include <math.h>

#define Bn 256
#define Sn 512
#define En 768
#define G3n 2304

typedef __attribute__((ext_vector_type(8))) short short8;   // 8 bf16 in 4 VGPRs
typedef __attribute__((ext_vector_type(4))) float f32x4;

__device__ __forceinline__ float sigmoidf_(float x) { return 1.f / (1.f + __expf(-x)); }
__device__ __forceinline__ float tanhf_(float x) {
  float e = __expf(2.f * x);
  return (e - 1.f) / (e + 1.f);
}

__device__ __forceinline__ unsigned short f2bf(float x) {
  unsigned int u = __builtin_bit_cast(unsigned int, x);
  u += 0x7FFFu + ((u >> 16) & 1u);          // round-to-nearest-even
  return (unsigned short)(u >> 16);
}
__device__ __forceinline__ float bf2f(unsigned short u) {
  unsigned int x = ((unsigned int)u) << 16;
  return __builtin_bit_cast(float, x);
}

// location weighting: u (position feature), w (memory weight)
__device__ __forceinline__ void loc_uw(int s, int start, int al, int ml, float& u, float& w) {
  float uu;
  if (s < start)            uu = (float)(s - start);
  else if (s < start + al)  uu = 0.f;
  else                      uu = (float)(s - start - al + 1);
  float l = fabsf(uu);
  if (s < ml) { w = 1.f - l / (float)ml; u = uu; }
  else        { w = 1.f; u = 0.f; }
}

// ================ K1: mega kernel =================
// blocks [0,512):  attention halves — block = (b, half of 256 rows), 16 waves,
//                  16 rows/wave online softmax; emits unnormalized (M,Z,IU,acc).
// blocks [512,944): GRU weight conversion f32 -> bf16 (216 blocks per matrix).
// block 512 additionally seeds out[] = dense_b (consumed by hop-3 atomics).
__global__ __launch_bounds__(1024) void k_mega(
    const float* __restrict__ mem, const float* __restrict__ att_w,
    const int* __restrict__ mlen, const int* __restrict__ llen, const int* __restrict__ alen,
    const float* __restrict__ w_ih, const float* __restrict__ w_hh,
    float* __restrict__ pacc, float* __restrict__ pm,
    float* __restrict__ pz, float* __restrict__ piu,
    unsigned short* __restrict__ wi_bf, unsigned short* __restrict__ wh_bf,
    const float* __restrict__ db, float* __restrict__ out) {
  __shared__ float accL[16][En];
  __shared__ float mL[16], zL[16], iuL[16];
  int bc = blockIdx.x;
  int tid = threadIdx.x;

  if (bc >= 512) {
    // ---- weight conversion role ----
    int cb = bc - 512;                 // [0,432)
    int mat = cb >= 216;
    int t = (cb - mat * 216) * 1024 + tid;
    int idx = t * 8;                   // [0, 2304*768)
    int r = idx / En, c = idx - r * En;
    const float* src;
    unsigned short* dst;
    if (mat == 0) { src = w_ih + (size_t)r * 769 + c; dst = wi_bf + idx; }
    else          { src = w_hh + (size_t)r * En  + c; dst = wh_bf + idx; }
    unsigned int p[4];
#pragma unroll
    for (int j = 0; j < 4; ++j) {
      unsigned int lo = f2bf(src[2 * j]);
      unsigned int hi = f2bf(src[2 * j + 1]);
      p[j] = lo | (hi << 16);
    }
    *reinterpret_cast<uint4*>(dst) = make_uint4(p[0], p[1], p[2], p[3]);
    if (bc == 512 && tid < 768) out[tid] = db[tid % 3];   // seed logits bias
    return;
  }

  // ---- attention role ----
  int b = bc >> 1, half = bc & 1;
  int wv = tid >> 6, lane = tid & 63;

  float4 w0 = *reinterpret_cast<const float4*>(att_w + lane * 4);
  float4 w1 = *reinterpret_cast<const float4*>(att_w + 256 + lane * 4);
  float4 w2 = *reinterpret_cast<const float4*>(att_w + 512 + lane * 4);
  float wtail = att_w[En];
  int start = llen[b], al = alen[b], ml = mlen[b];
  int s0row = half * 256 + wv * 16;
  const float* base = mem + ((size_t)b * Sn + s0row) * En;

  float m = -1e30f, z = 0.f, iu = 0.f;
  float4 a0 = {0, 0, 0, 0}, a1 = {0, 0, 0, 0}, a2 = {0, 0, 0, 0};
  float4 v0 = *reinterpret_cast<const float4*>(base + lane * 4);
  float4 v1 = *reinterpret_cast<const float4*>(base + 256 + lane * 4);
  float4 v2 = *reinterpret_cast<const float4*>(base + 512 + lane * 4);

  for (int r = 0; r < 16; ++r) {
    float4 c0 = v0, c1 = v1, c2 = v2;
    if (r < 15) {
      const float* nrow = base + (size_t)(r + 1) * En;
      v0 = *reinterpret_cast<const float4*>(nrow + lane * 4);
      v1 = *reinterpret_cast<const float4*>(nrow + 256 + lane * 4);
      v2 = *reinterpret_cast<const float4*>(nrow + 512 + lane * 4);
    }
    float dot = c0.x * w0.x + c0.y * w0.y + c0.z * w0.z + c0.w * w0.w
              + c1.x * w1.x + c1.y * w1.y + c1.z * w1.z + c1.w * w1.w
              + c2.x * w2.x + c2.y * w2.y + c2.z * w2.z + c2.w * w2.w;
#pragma unroll
    for (int off = 32; off; off >>= 1) dot += __shfl_xor(dot, off);
    int s = s0row + r;
    float u, w;
    loc_uw(s, start, al, ml, u, w);
    float g = w * dot + u * wtail;
    if (g > m) {                       // wave-uniform branch
      float f = __expf(m - g);         // first row: exp(-inf) = 0
      z *= f; iu *= f;
      a0.x *= f; a0.y *= f; a0.z *= f; a0.w *= f;
      a1.x *= f; a1.y *= f; a1.z *= f; a1.w *= f;
      a2.x *= f; a2.y *= f; a2.z *= f; a2.w *= f;
      m = g;
    }
    float e = __expf(g - m);
    z += e; iu += e * u;
    float sc = e * w;
    a0.x += sc * c0.x; a0.y += sc * c0.y; a0.z += sc * c0.z; a0.w += sc * c0.w;
    a1.x += sc * c1.x; a1.y += sc * c1.y; a1.z += sc * c1.z; a1.w += sc * c1.w;
    a2.x += sc * c2.x; a2.y += sc * c2.y; a2.z += sc * c2.z; a2.w += sc * c2.w;
  }

  *reinterpret_cast<float4*>(&accL[wv][lane * 4])       = a0;
  *reinterpret_cast<float4*>(&accL[wv][256 + lane * 4]) = a1;
  *reinterpret_cast<float4*>(&accL[wv][512 + lane * 4]) = a2;
  if (lane == 0) { mL[wv] = m; zL[wv] = z; iuL[wv] = iu; }
  __syncthreads();

  float M = mL[0];
#pragma unroll
  for (int i = 1; i < 16; ++i) M = fmaxf(M, mL[i]);
  float f[16], Z = 0.f, IU = 0.f;
#pragma unroll
  for (int i = 0; i < 16; ++i) {
    f[i] = __expf(mL[i] - M);
    Z += zL[i] * f[i];
    IU += iuL[i] * f[i];
  }
  if (tid < En) {
    float s = 0.f;
#pragma unroll
    for (int i = 0; i < 16; ++i) s += f[i] * accL[i][tid];
    pacc[(size_t)bc * En + tid] = s;
  }
  if (tid == 0) { pm[bc] = M; pz[bc] = Z; piu[bc] = IU; }
}

// ---------------- K2..K4: fused MFMA GEMM + GRU epilogue, split-K in block.
// Tile M=32 x E=32 x 3 gates; 512 thr = 8 waves. Waves 0-3 = fragment (wm,we)
// over k in [0,384); waves 4-7 = same fragments over k in [384,768).
// Stage BK=256 per iteration (3 iters). Split-K reduce reuses the Bs LDS
// (dead after MFMA) -> 68 KB total -> 2 blocks/CU.
// MODE 0: A built inline from attention partials (softmax combine, replaces
//         k_comb); adds position tail + b_ih, stores gi, GRU h=0 -> et.
// MODE 1: A = et_in bf16; full GRU from gi -> et.
// MODE 2: like 1 + fused logits via 16-lane reduce + atomicAdd into out.
template <int MODE>
__global__ __launch_bounds__(512) void k_fused(
    const float* __restrict__ pacc, const float* __restrict__ pm,
    const float* __restrict__ pz, const float* __restrict__ piu,
    const unsigned short* __restrict__ Abf, const unsigned short* __restrict__ Wbf,
    const float* __restrict__ w_ih, const float* __restrict__ b_ih,
    const float* __restrict__ b_hh, float* __restrict__ gi,
    unsigned short* __restrict__ et_out_bf,
    const float* __restrict__ dw, float* __restrict__ out) {
  __shared__ __align__(16) unsigned char lds[16896 + 50688];   // As | Bs(+red alias)
  auto As = reinterpret_cast<unsigned short(*)[264]>(lds);
  auto Bs = reinterpret_cast<unsigned short(*)[32][264]>(lds + 16896);
  float* red = reinterpret_cast<float*>(lds + 16896);          // [4][64][17] floats
  __shared__ float rowF0[32], rowF1[32], rowAu[32];

  int e0 = blockIdx.x * 32, m0 = blockIdx.y * 32;
  int tid = threadIdx.x;
  int lane = tid & 63, wv = tid >> 6;
  int p = wv & 3, kh = wv >> 2;
  int wm = p >> 1, we = p & 1;
  int l15 = lane & 15, l4 = lane >> 4;

  if (MODE == 0 && tid < 32) {
    int m = m0 + tid;
    float ma = pm[2 * m], mb = pm[2 * m + 1];
    float M = fmaxf(ma, mb);
    float f0 = __expf(ma - M), f1 = __expf(mb - M);
    float iv = 1.f / (pz[2 * m] * f0 + pz[2 * m + 1] * f1);
    rowF0[tid] = f0 * iv;
    rowF1[tid] = f1 * iv;
    rowAu[tid] = (piu[2 * m] * f0 + piu[2 * m + 1] * f1) * iv;
  }

  f32x4 acc[3];
#pragma unroll
  for (int g = 0; g < 3; ++g) { acc[g][0] = 0.f; acc[g][1] = 0.f; acc[g][2] = 0.f; acc[g][3] = 0.f; }

  for (int kb = 0; kb < 3; ++kb) {
    int kbase = kb * 256;
    __syncthreads();
    if (MODE == 0) {
#pragma unroll
      for (int i = 0; i < 2; ++i) {
        int idx = tid + i * 512;           // 32 rows x 32 chunks of 8 bf16
        int row = idx >> 5, ch = idx & 31;
        float f0 = rowF0[row], f1 = rowF1[row];
        const float* q0 = pacc + (size_t)(2 * (m0 + row)) * En + kbase + ch * 8;
        const float* q1 = q0 + En;
        float4 x0 = *reinterpret_cast<const float4*>(q0);
        float4 x1 = *reinterpret_cast<const float4*>(q0 + 4);
        float4 y0 = *reinterpret_cast<const float4*>(q1);
        float4 y1 = *reinterpret_cast<const float4*>(q1 + 4);
        unsigned int pk[4];
        pk[0] = (unsigned int)f2bf(f0 * x0.x + f1 * y0.x)
              | ((unsigned int)f2bf(f0 * x0.y + f1 * y0.y) << 16);
        pk[1] = (unsigned int)f2bf(f0 * x0.z + f1 * y0.z)
              | ((unsigned int)f2bf(f0 * x0.w + f1 * y0.w) << 16);
        pk[2] = (unsigned int)f2bf(f0 * x1.x + f1 * y1.x)
              | ((unsigned int)f2bf(f0 * x1.y + f1 * y1.y) << 16);
        pk[3] = (unsigned int)f2bf(f0 * x1.z + f1 * y1.z)
              | ((unsigned int)f2bf(f0 * x1.w + f1 * y1.w) << 16);
        *reinterpret_cast<uint4*>(&As[row][ch * 8]) = make_uint4(pk[0], pk[1], pk[2], pk[3]);
      }
    } else {
#pragma unroll
      for (int i = 0; i < 2; ++i) {
        int idx = tid + i * 512;
        int row = idx >> 5, ch = idx & 31;
        *reinterpret_cast<uint4*>(&As[row][ch * 8]) =
            *reinterpret_cast<const uint4*>(Abf + (size_t)(m0 + row) * En + kbase + ch * 8);
      }
    }
#pragma unroll
    for (int i = 0; i < 6; ++i) {
      int idx = tid + i * 512;             // 3 gates x 32 rows x 32 chunks
      int g = idx >> 10, rem = idx & 1023;
      int row = rem >> 5, ch = rem & 31;
      *reinterpret_cast<uint4*>(&Bs[g][row][ch * 8]) =
          *reinterpret_cast<const uint4*>(Wbf + (size_t)(g * En + e0 + row) * En + kbase + ch * 8);
    }
    __syncthreads();
#pragma unroll
    for (int ks = 0; ks < 4; ++ks) {
      int col = kh * 128 + ks * 32 + l4 * 8;
      short8 a = *reinterpret_cast<const short8*>(&As[wm * 16 + l15][col]);
#pragma unroll
      for (int g = 0; g < 3; ++g) {
        short8 bfr = *reinterpret_cast<const short8*>(&Bs[g][we * 16 + l15][col]);
        acc[g] = __builtin_amdgcn_mfma_f32_16x16x32_bf16(a, bfr, acc[g], 0, 0, 0);
      }
    }
  }

  // ---- split-K reduce (red aliases Bs; Bs reads are done) ----
  __syncthreads();
  if (kh == 1) {
#pragma unroll
    for (int g = 0; g < 3; ++g)
#pragma unroll
      for (int j = 0; j < 4; ++j) red[(p * 64 + lane) * 17 + g * 4 + j] = acc[g][j];
  }
  __syncthreads();
  if (kh == 1) return;
#pragma unroll
  for (int g = 0; g < 3; ++g)
#pragma unroll
    for (int j = 0; j < 4; ++j) acc[g][j] += red[(p * 64 + lane) * 17 + g * 4 + j];

  int ecol = e0 + we * 16 + l15;
  int mbase = m0 + wm * 16 + l4 * 4;
  float bhr = b_hh[ecol], bhz = b_hh[En + ecol], bhn = b_hh[2 * En + ecol];
  float vout[4];
  if (MODE == 0) {
    float wn0 = w_ih[(size_t)ecol * 769 + En];
    float wn1 = w_ih[(size_t)(En + ecol) * 769 + En];
    float wn2 = w_ih[(size_t)(2 * En + ecol) * 769 + En];
    float bi0 = b_ih[ecol], bi1 = b_ih[En + ecol], bi2 = b_ih[2 * En + ecol];
#pragma unroll
    for (int j = 0; j < 4; ++j) {
      int m = mbase + j;
      float au = rowAu[wm * 16 + l4 * 4 + j];
      float gr = acc[0][j] + au * wn0 + bi0;
      float gz = acc[1][j] + au * wn1 + bi1;
      float gn = acc[2][j] + au * wn2 + bi2;
      gi[(size_t)m * G3n + ecol]          = gr;
      gi[(size_t)m * G3n + En + ecol]     = gz;
      gi[(size_t)m * G3n + 2 * En + ecol] = gn;
      float r = sigmoidf_(gr + bhr);
      float z = sigmoidf_(gz + bhz);
      float n = tanhf_(gn + r * bhn);
      vout[j] = (1.f - z) * n;
    }
  } else {
#pragma unroll
    for (int j = 0; j < 4; ++j) {
      int m = mbase + j;
      float rr = sigmoidf_(gi[(size_t)m * G3n + ecol] + acc[0][j] + bhr);
      float zz = sigmoidf_(gi[(size_t)m * G3n + En + ecol] + acc[1][j] + bhz);
      float nn = tanhf_(gi[(size_t)m * G3n + 2 * En + ecol] + rr * (acc[2][j] + bhn));
      float h = bf2f(Abf[(size_t)m * En + ecol]);   // A IS et_in
      vout[j] = (1.f - zz) * nn + zz * h;
    }
  }

  if (MODE != 2) {
#pragma unroll
    for (int j = 0; j < 4; ++j)
      et_out_bf[(size_t)(mbase + j) * En + ecol] = f2bf(vout[j]);
  } else {
    // fused logits: partial over this thread's 1 col x 4 rows, reduce over the
    // 16-lane row-group (lanes sharing l4), one atomicAdd per (row, output).
    float dw0 = dw[ecol * 3 + 0], dw1 = dw[ecol * 3 + 1], dw2 = dw[ecol * 3 + 2];
    float pp[4][3];
#pragma unroll
    for (int j = 0; j < 4; ++j) {
      pp[j][0] = vout[j] * dw0;
      pp[j][1] = vout[j] * dw1;
      pp[j][2] = vout[j] * dw2;
    }
#pragma unroll
    for (int off = 1; off < 16; off <<= 1)
#pragma unroll
      for (int j = 0; j < 4; ++j) {
        pp[j][0] += __shfl_xor(pp[j][0], off);
        pp[j][1] += __shfl_xor(pp[j][1], off);
        pp[j][2] += __shfl_xor(pp[j][2], off);
      }
    if (l15 == 0) {
#pragma unroll
      for (int j = 0; j < 4; ++j) {
        atomicAdd(&out[(mbase + j) * 3 + 0], pp[j][0]);
        atomicAdd(&out[(mbase + j) * 3 + 1], pp[j][1]);
        atomicAdd(&out[(mbase + j) * 3 + 2], pp[j][2]);
      }
    }
  }
}

extern "C" void kernel_launch(void* const* d_in, const int* in_sizes, int n_in,
                              void* d_out, int out_size, void* d_ws, size_t ws_size,
                              hipStream_t stream) {
  const float* memory   = (const float*)d_in[0];
  const float* att_w    = (const float*)d_in[2];
  const float* gru_w_ih = (const float*)d_in[4];
  const float* gru_w_hh = (const float*)d_in[5];
  const float* gru_b_ih = (const float*)d_in[6];
  const float* gru_b_hh = (const float*)d_in[7];
  const float* dense_w  = (const float*)d_in[8];
  const float* dense_b  = (const float*)d_in[9];
  const int* memory_len = (const int*)d_in[10];
  const int* left_len   = (const int*)d_in[11];
  const int* aspect_len = (const int*)d_in[12];
  float* out = (float*)d_out;

  unsigned short* wi_bf  = (unsigned short*)d_ws;               // 2304*768
  unsigned short* wh_bf  = wi_bf + (size_t)G3n * En;            // 2304*768
  unsigned short* eta_bf = wh_bf + (size_t)G3n * En;            // 256*768
  unsigned short* etb_bf = eta_bf + (size_t)Bn * En;            // 256*768
  float* pm     = (float*)(etb_bf + (size_t)Bn * En);           // 512
  float* pz     = pm + 2 * Bn;                                  // 512
  float* piu    = pz + 2 * Bn;                                  // 512
  float* pacc   = piu + 2 * Bn;                                 // 512*768
  float* gi     = pacc + (size_t)2 * Bn * En;                   // 256*2304

  k_mega<<<dim3(944), 1024, 0, stream>>>(memory, att_w, memory_len, left_len, aspect_len,
                                         gru_w_ih, gru_w_hh, pacc, pm, pz, piu, wi_bf, wh_bf,
                                         dense_b, out);
  k_fused<0><<<dim3(En / 32, Bn / 32), 512, 0, stream>>>(
      pacc, pm, pz, piu, nullptr, wi_bf, gru_w_ih, gru_b_ih, gru_b_hh, gi, eta_bf,
      nullptr, nullptr);
  k_fused<1><<<dim3(En / 32, Bn / 32), 512, 0, stream>>>(
      nullptr, nullptr, nullptr, nullptr, eta_bf, wh_bf, nullptr, nullptr, gru_b_hh, gi, etb_bf,
      nullptr, nullptr);
  k_fused<2><<<dim3(En / 32, Bn / 32), 512, 0, stream>>>(
      nullptr, nullptr, nullptr, nullptr, etb_bf, wh_bf, nullptr, nullptr, gru_b_hh, gi, nullptr,
      dense_w, out);
}